// Round 8
// baseline (199.028 us; speedup 1.0000x reference)
//
#include <hip/hip_runtime.h>

#define DF 128
#define NBKT_MAX 256   // coarse buckets = ceil(N/256); N=50000 -> 196
#define CAP 8192       // per-bucket edge capacity incl. 8-align padding (avg 4082+<=1792 pad)
#define SCHUNK 2048    // edges per scatter block (R2: 8192 -> 3.6% occupancy, latency-bound)
// packing assumes src < 2^24 and N < 65535 (srcs stored as ushort; sentinel = N). N=50000.

typedef unsigned int uint;
typedef unsigned short ushort;
typedef __attribute__((ext_vector_type(8))) short short8;   // 8 bf16 (4 VGPR) MFMA A/B frag
typedef __attribute__((ext_vector_type(4))) float f32x4;    // MFMA C/D frag

union frag_u { uint4 u4; short8 s8; };

__device__ __forceinline__ uint f2u(float f) { return __float_as_uint(f); }
__device__ __forceinline__ ushort rne_bf16(float v) {
    uint u = __float_as_uint(v);
    u = u + 0x7FFFu + ((u >> 16) & 1u);
    return (ushort)(u >> 16);
}
__device__ __forceinline__ float bflo(uint u) { return __uint_as_float(u << 16); }
__device__ __forceinline__ float bfhi(uint u) { return __uint_as_float(u & 0xFFFF0000u); }

// ============ scatter + wprep fused (R3/R5 proven; R7: do NOT overlap gemm1 here) ============
__global__ __launch_bounds__(256) void scatter_wprep(const int* __restrict__ src,
                                                     const int* __restrict__ dst,
                                                     int* __restrict__ ccur,
                                                     uint* __restrict__ ebuf,
                                                     int E, int NB, int SB,
                                                     const float* __restrict__ W1,
                                                     const float* __restrict__ W2,
                                                     uint4* __restrict__ Whi,
                                                     uint4* __restrict__ Wlo) {
    __shared__ int cnt[NBKT_MAX];
    __shared__ int base[NBKT_MAX];
    int t = threadIdx.x;
    if ((int)blockIdx.x < SB) {
        int e0 = blockIdx.x * SCHUNK;
        int eb0 = e0 + t * 8;                       // this thread's 8 contiguous edges
        int lim = min(E - eb0, 8);                  // <8 only in last block
        int d[8], s[8];
        if (lim == 8) {
            int4 d0 = *(const int4*)(dst + eb0), d1 = *(const int4*)(dst + eb0 + 4);
            int4 s0 = *(const int4*)(src + eb0), s1 = *(const int4*)(src + eb0 + 4);
            d[0] = d0.x; d[1] = d0.y; d[2] = d0.z; d[3] = d0.w;
            d[4] = d1.x; d[5] = d1.y; d[6] = d1.z; d[7] = d1.w;
            s[0] = s0.x; s[1] = s0.y; s[2] = s0.z; s[3] = s0.w;
            s[4] = s1.x; s[5] = s1.y; s[6] = s1.z; s[7] = s1.w;
        } else {
            for (int i = 0; i < 8; ++i) { d[i] = 0; s[i] = 0; }
            for (int i = 0; i < lim; ++i) { d[i] = dst[eb0 + i]; s[i] = src[eb0 + i]; }
        }
        for (int i = t; i < NB; i += 256) cnt[i] = 0;
        __syncthreads();
        for (int i = 0; i < 8; ++i)
            if (i < lim) atomicAdd(&cnt[d[i] >> 8], 1);
        __syncthreads();
        for (int i = t; i < NB; i += 256) base[i] = cnt[i] ? atomicAdd(&ccur[i], cnt[i]) : 0;
        __syncthreads();
        for (int i = 0; i < 8; ++i)
            if (i < lim) {
                int b = d[i] >> 8;
                int pos = atomicAdd(&base[b], 1);
                if (pos < CAP) ebuf[(size_t)b * CAP + pos] = ((uint)(d[i] & 255) << 24) | (uint)s[i];
            }
    } else {
        int tt4 = ((int)blockIdx.x - SB) * 256 + t;   // 0..4095
        int wsel = tt4 >> 11;
        int tt = tt4 & 2047;
        const float* W = wsel ? W2 : W1;
        int lane = tt & 63;
        int n  = ((tt >> 6) & 7) * 16 + (lane & 15);
        int k0 = (tt >> 9) * 32 + (lane >> 4) * 8;
        uint hi[4], lo[4];
#pragma unroll
        for (int p = 0; p < 4; ++p) {
            float f0 = W[(size_t)(k0 + 2 * p) * DF + n];
            float f1 = W[(size_t)(k0 + 2 * p + 1) * DF + n];
            uint u0 = f2u(f0), u1 = f2u(f1);
            hi[p] = (u1 & 0xFFFF0000u) | (u0 >> 16);                 // truncation split
            float l0 = f0 - __uint_as_float(u0 & 0xFFFF0000u);       // exact residual
            float l1 = f1 - __uint_as_float(u1 & 0xFFFF0000u);
            lo[p] = (f2u(l1) & 0xFFFF0000u) | (f2u(l0) >> 16);
        }
        Whi[wsel * 2048 + tt] = make_uint4(hi[0], hi[1], hi[2], hi[3]);
        Wlo[wsel * 2048 + tt] = make_uint4(lo[0], lo[1], lo[2], lo[3]);
    }
}

// ============ fused: bucket sort (8-pad sentinel segments) || layer-1 GEMM (UNSCALED) =====
// R5 proven (189.5us). Init extended: zero sentinel rows of BOTH Hq (layer1) and Hq2
// (layer2 double-buffer, new in R8 to allow gather1 || gemm2 overlap) + dinv[N]=0.
__global__ __launch_bounds__(256) void sort_gemm1(const uint* __restrict__ ebuf,
                                                  const int* __restrict__ ccur,
                                                  int* __restrict__ rstart,
                                                  int* __restrict__ rend,
                                                  float* __restrict__ dinv,
                                                  ushort* __restrict__ srcs,
                                                  const float* __restrict__ A,
                                                  const uint4* __restrict__ Bhi,
                                                  const uint4* __restrict__ Blo,
                                                  ushort* __restrict__ Hq,
                                                  ushort* __restrict__ Hq2,
                                                  int NB, int N) {
    __shared__ int cnt[256];
    __shared__ int sp[256];
    int t = threadIdx.x;
    if ((int)blockIdx.x < NB) {
        // ---------- bucket sort with 8-aligned, sentinel-padded per-node segments ----------
        int b = blockIdx.x;
        int count = min(ccur[b], CAP);
        const uint* eb = ebuf + (size_t)b * CAP;
        if (b == 0) {                        // one-time: zero dummy rows + dinv sentinel
            if (t < 16) {                    // Hq: 4 quarters x 64B dummy row (stride N+1)
                size_t byteoff = ((size_t)(t >> 2) * (N + 1) + N) * 64 + (size_t)(t & 3) * 16;
                *(uint4*)((char*)Hq + byteoff) = make_uint4(0u, 0u, 0u, 0u);
            } else if (t < 32) {             // Hq2: same
                int tz = t - 16;
                size_t byteoff = ((size_t)(tz >> 2) * (N + 1) + N) * 64 + (size_t)(tz & 3) * 16;
                *(uint4*)((char*)Hq2 + byteoff) = make_uint4(0u, 0u, 0u, 0u);
            } else if (t == 32) {
                dinv[N] = 0.0f;              // sentinel scale = 0
            }
        }
        cnt[t] = 0;
        __syncthreads();
        for (int j = t; j < count; j += 256) atomicAdd(&cnt[eb[j] >> 24], 1);
        __syncthreads();
        int v = cnt[t];
        int pv = (v + 7) & ~7;              // padded to multiple of 8
        sp[t] = pv;
        __syncthreads();
        for (int off = 1; off < 256; off <<= 1) {
            int x = (t >= off) ? sp[t - off] : 0;
            __syncthreads();
            sp[t] += x;
            __syncthreads();
        }
        int ex = sp[t] - pv;                // exclusive padded offset (multiple of 8)
        int node = b * 256 + t;
        if (node < N) {
            rstart[node] = b * CAP + ex;
            rend[node]   = b * CAP + ex + v;
            dinv[node] = rsqrtf((float)v + 1.0f);   // +1 = self-loop
        }
        // sentinel-fill this node's pad slots (disjoint from all real scatter targets)
        for (int p = ex + v; p < ex + pv && p < CAP; ++p)
            srcs[(size_t)b * CAP + p] = (ushort)N;
        sp[t] = ex;                          // becomes local cursor
        __syncthreads();
        for (int j = t; j < count; j += 256) {
            uint e = eb[j];
            int pos = atomicAdd(&sp[e >> 24], 1);
            if (pos < CAP) srcs[(size_t)b * CAP + pos] = (ushort)(e & 0xFFFFFFu);
        }
    } else {
        // ---------- layer-1 GEMM, fp32 A, 3-product split, UNSCALED output ----------
        const int lane = t & 63;
        const int w = t >> 6;
        const int l15 = lane & 15, quad = lane >> 4;
        const int rowbase = ((int)blockIdx.x - NB) * 128 + w * 32;
        const int M = N;

        f32x4 acc[2][8];
#pragma unroll
        for (int rt = 0; rt < 2; ++rt)
#pragma unroll
            for (int ct = 0; ct < 8; ++ct) acc[rt][ct] = (f32x4){0.f, 0.f, 0.f, 0.f};

        for (int q = 0; q < 4; ++q) {
            frag_u ah[2], al[2];
#pragma unroll
            for (int rt = 0; rt < 2; ++rt) {
                int m = rowbase + rt * 16 + l15;
                if (m >= M) m = M - 1;                  // clamp; stores guarded below
                const float* ap = A + (size_t)m * DF + q * 32 + quad * 8;
                float4 v0 = *(const float4*)ap;
                float4 v1 = *(const float4*)(ap + 4);
                float f[8] = {v0.x, v0.y, v0.z, v0.w, v1.x, v1.y, v1.z, v1.w};
                uint hi[4], lo[4];
#pragma unroll
                for (int p = 0; p < 4; ++p) {
                    uint u0 = f2u(f[2 * p]), u1 = f2u(f[2 * p + 1]);
                    hi[p] = (u1 & 0xFFFF0000u) | (u0 >> 16);
                    float l0 = f[2 * p]     - __uint_as_float(u0 & 0xFFFF0000u);
                    float l1 = f[2 * p + 1] - __uint_as_float(u1 & 0xFFFF0000u);
                    lo[p] = (f2u(l1) & 0xFFFF0000u) | (f2u(l0) >> 16);
                }
                ah[rt].u4 = make_uint4(hi[0], hi[1], hi[2], hi[3]);
                al[rt].u4 = make_uint4(lo[0], lo[1], lo[2], lo[3]);
            }
#pragma unroll
            for (int ct = 0; ct < 8; ++ct) {
                frag_u bh, bl;
                bh.u4 = Bhi[(q * 8 + ct) * 64 + lane];
                bl.u4 = Blo[(q * 8 + ct) * 64 + lane];
#pragma unroll
                for (int rt = 0; rt < 2; ++rt) {
                    acc[rt][ct] = __builtin_amdgcn_mfma_f32_16x16x32_bf16(al[rt].s8, bh.s8, acc[rt][ct], 0, 0, 0);
                    acc[rt][ct] = __builtin_amdgcn_mfma_f32_16x16x32_bf16(ah[rt].s8, bl.s8, acc[rt][ct], 0, 0, 0);
                    acc[rt][ct] = __builtin_amdgcn_mfma_f32_16x16x32_bf16(ah[rt].s8, bh.s8, acc[rt][ct], 0, 0, 0);
                }
            }
        }
        // epilogue: col = ct*16+l15 -> q = ct>>1, d = (ct&1)*16+l15; row = rt*16+quad*4+reg
        // quarter tables have stride M+1 (row M = zeroed sentinel row)
#pragma unroll
        for (int rt = 0; rt < 2; ++rt)
#pragma unroll
            for (int reg = 0; reg < 4; ++reg) {
                int row = rowbase + rt * 16 + quad * 4 + reg;
                if (row < M) {
#pragma unroll
                    for (int ct = 0; ct < 8; ++ct)
                        Hq[((size_t)(ct >> 1) * (M + 1) + row) * 32 + (ct & 1) * 16 + l15] =
                            rne_bf16(acc[rt][ct][reg]);
                }
            }
    }
}

// ---------- layer-2 GEMM block body (bf16 A quarter-major, dinv-scaled) ----------
__device__ __forceinline__ void gemm2_body(int gb, int t,
                                           const ushort* A,
                                           const uint4* __restrict__ Bhi,
                                           const uint4* __restrict__ Blo,
                                           const float* __restrict__ dinv,
                                           ushort* Hq, int M) {
    const int lane = t & 63;
    const int w = t >> 6;
    const int l15 = lane & 15, quad = lane >> 4;
    const int rowbase = gb * 128 + w * 32;

    f32x4 acc[2][8];
#pragma unroll
    for (int rt = 0; rt < 2; ++rt)
#pragma unroll
        for (int ct = 0; ct < 8; ++ct) acc[rt][ct] = (f32x4){0.f, 0.f, 0.f, 0.f};

    for (int q = 0; q < 4; ++q) {
        frag_u a[2];
#pragma unroll
        for (int rt = 0; rt < 2; ++rt) {
            int m = rowbase + rt * 16 + l15;
            if (m >= M) m = M - 1;
            const ushort* ap = A + ((size_t)q * M + m) * 32 + quad * 8;
            a[rt].u4 = *(const uint4*)ap;
        }
#pragma unroll
        for (int ct = 0; ct < 8; ++ct) {
            frag_u bh, bl;
            bh.u4 = Bhi[(q * 8 + ct) * 64 + lane];
            bl.u4 = Blo[(q * 8 + ct) * 64 + lane];
#pragma unroll
            for (int rt = 0; rt < 2; ++rt) {
                acc[rt][ct] = __builtin_amdgcn_mfma_f32_16x16x32_bf16(a[rt].s8, bl.s8, acc[rt][ct], 0, 0, 0);
                acc[rt][ct] = __builtin_amdgcn_mfma_f32_16x16x32_bf16(a[rt].s8, bh.s8, acc[rt][ct], 0, 0, 0);
            }
        }
    }
#pragma unroll
    for (int rt = 0; rt < 2; ++rt)
#pragma unroll
        for (int reg = 0; reg < 4; ++reg) {
            int row = rowbase + rt * 16 + quad * 4 + reg;
            if (row < M) {
                float di = dinv[row];
#pragma unroll
                for (int ct = 0; ct < 8; ++ct)
                    Hq[((size_t)(ct >> 1) * (M + 1) + row) * 32 + (ct & 1) * 16 + l15] =
                        rne_bf16(acc[rt][ct][reg] * di);
            }
        }
}

__global__ __launch_bounds__(256) void gemm_bf16A(const ushort* __restrict__ A,
                                                  const uint4* __restrict__ Bhi,
                                                  const uint4* __restrict__ Blo,
                                                  const float* __restrict__ dinv,
                                                  ushort* __restrict__ Hq, int M, int gb0) {
    gemm2_body((int)blockIdx.x + gb0, threadIdx.x, A, Bhi, Blo, dinv, Hq, M);
}

// ---------- quarter-gather block body (R5 proven: tail-free 8-wide, 8 rows in flight) ----------
template<bool L1>
__device__ __forceinline__ void gather_body(int chunk, int sub, int t,
                                            const uint4* H4,
                                            const float* __restrict__ dinv,
                                            const int* __restrict__ rstart,
                                            const int* __restrict__ rend,
                                            const ushort* __restrict__ srcs,
                                            const float* __restrict__ bias,
                                            void* outv, int N) {
    int q = sub >> 1;
    int n = chunk * 128 + (sub & 1) * 64 + (t >> 2);        // one dst per 4-lane group
    if (n >= N) return;
    int l = t & 3;                                          // lane's uint4 within 64B row
    const uint4* Hq4 = H4 + (size_t)q * (N + 1) * 4;        // quarter table, stride N+1

    float4 bb0 = ((const float4*)bias)[q * 8 + l * 2];
    float4 bb1 = ((const float4*)bias)[q * 8 + l * 2 + 1];

    float di = dinv[n];
    uint4 self = Hq4[(size_t)n * 4 + l];                    // self-loop row
    float sc = L1 ? di : 1.0f;                              // L1: Hq unscaled -> self*di
    float a0 = bflo(self.x) * sc, a1 = bfhi(self.x) * sc, a2 = bflo(self.y) * sc, a3 = bfhi(self.y) * sc;
    float a4 = bflo(self.z) * sc, a5 = bfhi(self.z) * sc, a6 = bflo(self.w) * sc, a7 = bfhi(self.w) * sc;

    int j = rstart[n];
    int niter = (rend[n] - j + 7) >> 3;                     // padded trip count (no tail!)
    uint4 sv;
    if (niter > 0) sv = *(const uint4*)(srcs + j);
    for (int g = 0; g < niter; ++g) {
        uint4 svc = sv;
        if (g + 1 < niter) sv = *(const uint4*)(srcs + j + 8);   // prefetch next group
        int si[8];
        si[0] = svc.x & 0xFFFF; si[1] = svc.x >> 16;
        si[2] = svc.y & 0xFFFF; si[3] = svc.y >> 16;
        si[4] = svc.z & 0xFFFF; si[5] = svc.z >> 16;
        si[6] = svc.w & 0xFFFF; si[7] = svc.w >> 16;
        uint4 v[8];
#pragma unroll
        for (int i = 0; i < 8; ++i) v[i] = Hq4[(size_t)si[i] * 4 + l];
        if constexpr (L1) {
            float dd[8];
#pragma unroll
            for (int i = 0; i < 8; ++i) dd[i] = dinv[si[i]];    // sentinel -> 0.0f
#pragma unroll
            for (int i = 0; i < 8; ++i) {
                a0 = fmaf(bflo(v[i].x), dd[i], a0); a1 = fmaf(bfhi(v[i].x), dd[i], a1);
                a2 = fmaf(bflo(v[i].y), dd[i], a2); a3 = fmaf(bfhi(v[i].y), dd[i], a3);
                a4 = fmaf(bflo(v[i].z), dd[i], a4); a5 = fmaf(bfhi(v[i].z), dd[i], a5);
                a6 = fmaf(bflo(v[i].w), dd[i], a6); a7 = fmaf(bfhi(v[i].w), dd[i], a7);
            }
        } else {
#pragma unroll
            for (int i = 0; i < 8; ++i) {                       // sentinel rows are zero
                a0 += bflo(v[i].x); a1 += bfhi(v[i].x);
                a2 += bflo(v[i].y); a3 += bfhi(v[i].y);
                a4 += bflo(v[i].z); a5 += bfhi(v[i].z);
                a6 += bflo(v[i].w); a7 += bfhi(v[i].w);
            }
        }
        j += 8;
    }
    float o0 = fmaf(a0, di, bb0.x), o1 = fmaf(a1, di, bb0.y);
    float o2 = fmaf(a2, di, bb0.z), o3 = fmaf(a3, di, bb0.w);
    float o4 = fmaf(a4, di, bb1.x), o5 = fmaf(a5, di, bb1.y);
    float o6 = fmaf(a6, di, bb1.z), o7 = fmaf(a7, di, bb1.w);
    if (L1) {
        o0 = fmaxf(o0, 0.f); o1 = fmaxf(o1, 0.f); o2 = fmaxf(o2, 0.f); o3 = fmaxf(o3, 0.f);
        o4 = fmaxf(o4, 0.f); o5 = fmaxf(o5, 0.f); o6 = fmaxf(o6, 0.f); o7 = fmaxf(o7, 0.f);
        uint4 pk;
        pk.x = (uint)rne_bf16(o0) | ((uint)rne_bf16(o1) << 16);
        pk.y = (uint)rne_bf16(o2) | ((uint)rne_bf16(o3) << 16);
        pk.z = (uint)rne_bf16(o4) | ((uint)rne_bf16(o5) << 16);
        pk.w = (uint)rne_bf16(o6) | ((uint)rne_bf16(o7) << 16);
        ((uint4*)outv)[((size_t)q * N + n) * 4 + l] = pk;      // Z1 keeps stride N
    } else {
        float4* op = (float4*)((float*)outv + (size_t)n * DF + q * 32 + l * 8);
        op[0] = make_float4(o0, o1, o2, o3);
        op[1] = make_float4(o4, o5, o6, o7);
    }
}

template<bool L1>
__global__ __launch_bounds__(256) void quarter_gather(const uint4* __restrict__ H4,
                                                      const float* __restrict__ dinv,
                                                      const int* __restrict__ rstart,
                                                      const int* __restrict__ rend,
                                                      const ushort* __restrict__ srcs,
                                                      const float* __restrict__ bias,
                                                      void* __restrict__ outv, int N,
                                                      int chunk0) {
    gather_body<L1>(((int)blockIdx.x >> 3) + chunk0, (int)blockIdx.x & 7, threadIdx.x,
                    H4, dinv, rstart, rend, srcs, bias, outv, N);
}

// ============ D3b: gather1 chunks [C1,TC) || gemm2 rows [0, C1*128) ============
// gemm2 is row-local (row m needs only Z1 row m), so the first row-half can run while
// gather1 finishes the second node-half. Layer 2 writes Hq2 (double buffer) — gather1b
// still reads random rows of Hq, so gemm2 must NOT overwrite Hq (R8 correctness fix).
__global__ __launch_bounds__(256) void gather1_gemm2(const uint4* H4,
                                                     const float* __restrict__ dinv,
                                                     const int* __restrict__ rstart,
                                                     const int* __restrict__ rend,
                                                     const ushort* __restrict__ srcs,
                                                     const float* __restrict__ b1,
                                                     ushort* Z1,
                                                     const uint4* __restrict__ Bhi2,
                                                     const uint4* __restrict__ Blo2,
                                                     ushort* Hq2,
                                                     int C1, int G2A, int N) {
    if ((int)blockIdx.x < G2A) {
        gemm2_body((int)blockIdx.x, threadIdx.x, (const ushort*)Z1, Bhi2, Blo2, dinv, Hq2, N);
    } else {
        int b = (int)blockIdx.x - G2A;
        gather_body<true>((b >> 3) + C1, b & 7, threadIdx.x,
                          H4, dinv, rstart, rend, srcs, b1, (void*)Z1, N);
    }
}

extern "C" void kernel_launch(void* const* d_in, const int* in_sizes, int n_in,
                              void* d_out, int out_size, void* d_ws, size_t ws_size,
                              hipStream_t stream) {
    const float* x  = (const float*)d_in[0];
    const int*   ei = (const int*)d_in[1];
    const float* W1 = (const float*)d_in[2];
    const float* b1 = (const float*)d_in[3];
    const float* W2 = (const float*)d_in[4];
    const float* b2 = (const float*)d_in[5];

    const int N = in_sizes[0] / DF;     // 50000
    const int E = in_sizes[1] / 2;      // 800000
    const int* src = ei;
    const int* dstp = ei + E;
    const int NB = (N + 255) >> 8;      // 196 coarse buckets
    const int SB = (E + SCHUNK - 1) / SCHUNK;   // 391 scatter blocks

    float* out = (float*)d_out;
    char* ws = (char*)d_ws;
    size_t off = 0;
    auto carve = [&](size_t bytes) { void* p = ws + off; off += (bytes + 255) & ~(size_t)255; return p; };
    ushort* Hq     = (ushort*)carve((size_t)4 * (N + 1) * 32 * sizeof(ushort));   // 12.8 MB, stride N+1
    ushort* Hq2    = (ushort*)carve((size_t)4 * (N + 1) * 32 * sizeof(ushort));   // 12.8 MB (layer-2 dbuf)
    ushort* Z1     = (ushort*)carve((size_t)N * DF * sizeof(ushort));             // 12.8 MB, stride N
    float*  dinv   = (float*)carve((size_t)(N + 1) * sizeof(float));              // + sentinel slot
    int*    rstart = (int*)carve((size_t)N * sizeof(int));
    int*    rend   = (int*)carve((size_t)N * sizeof(int));
    uint*   ebuf   = (uint*)carve((size_t)NB * CAP * sizeof(uint));               // 6.4 MB
    ushort* srcs   = (ushort*)carve((size_t)NB * CAP * sizeof(ushort));           // 3.2 MB
    int*    ccur   = (int*)carve(NBKT_MAX * sizeof(int));
    uint4*  Whi    = (uint4*)carve(2 * 2048 * sizeof(uint4));                     // 64 KB
    uint4*  Wlo    = (uint4*)carve(2 * 2048 * sizeof(uint4));                     // 64 KB

    const int TC = (N + 127) / 128;             // 391 node chunks (128 nodes each)
    const int C1 = (TC + 1) / 2;                // 196 chunks in gather1a; gemm2a rows [0, C1*128)

    // ---- D1: CSR scatter (scan-free, regs-cached edges) + W split ----
    hipMemsetAsync(ccur, 0, NBKT_MAX * sizeof(int), stream);
    scatter_wprep<<<SB + 16, 256, 0, stream>>>(src, dstp, ccur, ebuf, E, NB, SB, W1, W2, Whi, Wlo);

    // ---- D2: bucket sort (sentinel-padded segments) || ALL of layer-1 GEMM ----
    sort_gemm1<<<NB + TC, 256, 0, stream>>>(ebuf, ccur, rstart, rend, dinv, srcs,
                                            x, Whi, Wlo, Hq, Hq2, NB, N);

    // ---- D3a: layer-1 gather, node chunks [0, C1) ----
    quarter_gather<true><<<C1 * 8, 256, 0, stream>>>((const uint4*)Hq, dinv, rstart, rend,
                                                     srcs, b1, Z1, N, 0);

    // ---- D3b: layer-1 gather chunks [C1, TC) || layer-2 GEMM rows [0, C1*128) ----
    gather1_gemm2<<<C1 + (TC - C1) * 8, 256, 0, stream>>>((const uint4*)Hq, dinv, rstart, rend,
                                                          srcs, b1, Z1, Whi + 2048, Wlo + 2048,
                                                          Hq2, C1, C1, N);

    // ---- D3c: layer-2 GEMM rows [C1*128, N) ----
    gemm_bf16A<<<TC - C1, 256, 0, stream>>>(Z1, Whi + 2048, Wlo + 2048, dinv, Hq2, N, C1);

    // ---- D4: layer-2 gather: out = gather(Hq2)*di + b2 ----
    quarter_gather<false><<<TC * 8, 256, 0, stream>>>((const uint4*)Hq2, dinv, rstart, rend,
                                                      srcs, b2, out, N, 0);
}

// Round 9
// 197.527 us; speedup vs baseline: 1.0076x; 1.0076x over previous
//
#include <hip/hip_runtime.h>

#define DF 128
#define NBKT_MAX 256   // coarse buckets = ceil(N/256); N=50000 -> 196
#define CAP 8192       // per-bucket edge capacity incl. 8-align padding (avg 4082+<=1792 pad)
#define SCHUNK 2048    // edges per scatter block (R2: 8192 -> 3.6% occupancy, latency-bound)
// packing assumes src < 2^24 and N < 65535 (srcs stored as ushort; sentinel = N). N=50000.

typedef unsigned int uint;
typedef unsigned short ushort;
typedef __attribute__((ext_vector_type(8))) short short8;   // 8 bf16 (4 VGPR) MFMA A/B frag
typedef __attribute__((ext_vector_type(4))) float f32x4;    // MFMA C/D frag

union frag_u { uint4 u4; short8 s8; };

__device__ __forceinline__ uint f2u(float f) { return __float_as_uint(f); }
__device__ __forceinline__ ushort rne_bf16(float v) {
    uint u = __float_as_uint(v);
    u = u + 0x7FFFu + ((u >> 16) & 1u);
    return (ushort)(u >> 16);
}
__device__ __forceinline__ float bflo(uint u) { return __uint_as_float(u << 16); }
__device__ __forceinline__ float bfhi(uint u) { return __uint_as_float(u & 0xFFFF0000u); }

// ============ scatter + wprep fused (R3/R5 proven) ============
__global__ __launch_bounds__(256) void scatter_wprep(const int* __restrict__ src,
                                                     const int* __restrict__ dst,
                                                     int* __restrict__ ccur,
                                                     uint* __restrict__ ebuf,
                                                     int E, int NB, int SB,
                                                     const float* __restrict__ W1,
                                                     const float* __restrict__ W2,
                                                     uint4* __restrict__ Whi,
                                                     uint4* __restrict__ Wlo) {
    __shared__ int cnt[NBKT_MAX];
    __shared__ int base[NBKT_MAX];
    int t = threadIdx.x;
    if ((int)blockIdx.x < SB) {
        int e0 = blockIdx.x * SCHUNK;
        int eb0 = e0 + t * 8;                       // this thread's 8 contiguous edges
        int lim = min(E - eb0, 8);                  // <8 only in last block
        int d[8], s[8];
        if (lim == 8) {
            int4 d0 = *(const int4*)(dst + eb0), d1 = *(const int4*)(dst + eb0 + 4);
            int4 s0 = *(const int4*)(src + eb0), s1 = *(const int4*)(src + eb0 + 4);
            d[0] = d0.x; d[1] = d0.y; d[2] = d0.z; d[3] = d0.w;
            d[4] = d1.x; d[5] = d1.y; d[6] = d1.z; d[7] = d1.w;
            s[0] = s0.x; s[1] = s0.y; s[2] = s0.z; s[3] = s0.w;
            s[4] = s1.x; s[5] = s1.y; s[6] = s1.z; s[7] = s1.w;
        } else {
            for (int i = 0; i < 8; ++i) { d[i] = 0; s[i] = 0; }
            for (int i = 0; i < lim; ++i) { d[i] = dst[eb0 + i]; s[i] = src[eb0 + i]; }
        }
        for (int i = t; i < NB; i += 256) cnt[i] = 0;
        __syncthreads();
        for (int i = 0; i < 8; ++i)
            if (i < lim) atomicAdd(&cnt[d[i] >> 8], 1);
        __syncthreads();
        for (int i = t; i < NB; i += 256) base[i] = cnt[i] ? atomicAdd(&ccur[i], cnt[i]) : 0;
        __syncthreads();
        for (int i = 0; i < 8; ++i)
            if (i < lim) {
                int b = d[i] >> 8;
                int pos = atomicAdd(&base[b], 1);
                if (pos < CAP) ebuf[(size_t)b * CAP + pos] = ((uint)(d[i] & 255) << 24) | (uint)s[i];
            }
    } else {
        int tt4 = ((int)blockIdx.x - SB) * 256 + t;   // 0..4095
        int wsel = tt4 >> 11;
        int tt = tt4 & 2047;
        const float* W = wsel ? W2 : W1;
        int lane = tt & 63;
        int n  = ((tt >> 6) & 7) * 16 + (lane & 15);
        int k0 = (tt >> 9) * 32 + (lane >> 4) * 8;
        uint hi[4], lo[4];
#pragma unroll
        for (int p = 0; p < 4; ++p) {
            float f0 = W[(size_t)(k0 + 2 * p) * DF + n];
            float f1 = W[(size_t)(k0 + 2 * p + 1) * DF + n];
            uint u0 = f2u(f0), u1 = f2u(f1);
            hi[p] = (u1 & 0xFFFF0000u) | (u0 >> 16);                 // truncation split
            float l0 = f0 - __uint_as_float(u0 & 0xFFFF0000u);       // exact residual
            float l1 = f1 - __uint_as_float(u1 & 0xFFFF0000u);
            lo[p] = (f2u(l1) & 0xFFFF0000u) | (f2u(l0) >> 16);
        }
        Whi[wsel * 2048 + tt] = make_uint4(hi[0], hi[1], hi[2], hi[3]);
        Wlo[wsel * 2048 + tt] = make_uint4(lo[0], lo[1], lo[2], lo[3]);
    }
}

// ============ fused: bucket sort (8-pad sentinel segments) || layer-1 GEMM (UNSCALED) =====
// R5 proven structure (189.5us). R7/R8 lesson: only this overlap (sort||gemm1) pays;
// anything co-scheduled with scatter or a gather interferes.
__global__ __launch_bounds__(256) void sort_gemm1(const uint* __restrict__ ebuf,
                                                  const int* __restrict__ ccur,
                                                  int* __restrict__ rstart,
                                                  int* __restrict__ rend,
                                                  float* __restrict__ dinv,
                                                  ushort* __restrict__ srcs,
                                                  const float* __restrict__ A,
                                                  const uint4* __restrict__ Bhi,
                                                  const uint4* __restrict__ Blo,
                                                  ushort* __restrict__ Hq,
                                                  int NB, int N) {
    __shared__ int cnt[256];
    __shared__ int sp[256];
    int t = threadIdx.x;
    if ((int)blockIdx.x < NB) {
        // ---------- bucket sort with 8-aligned, sentinel-padded per-node segments ----------
        int b = blockIdx.x;
        int count = min(ccur[b], CAP);
        const uint* eb = ebuf + (size_t)b * CAP;
        if (b == 0) {                        // one-time: zero dummy rows + dinv sentinel
            if (t < 16) {                    // 4 quarters x 64B dummy row (stride N+1)
                size_t byteoff = ((size_t)(t >> 2) * (N + 1) + N) * 64 + (size_t)(t & 3) * 16;
                *(uint4*)((char*)Hq + byteoff) = make_uint4(0u, 0u, 0u, 0u);
            } else if (t == 16) {
                dinv[N] = 0.0f;              // sentinel scale = 0
            }
        }
        cnt[t] = 0;
        __syncthreads();
        for (int j = t; j < count; j += 256) atomicAdd(&cnt[eb[j] >> 24], 1);
        __syncthreads();
        int v = cnt[t];
        int pv = (v + 7) & ~7;              // padded to multiple of 8
        sp[t] = pv;
        __syncthreads();
        for (int off = 1; off < 256; off <<= 1) {
            int x = (t >= off) ? sp[t - off] : 0;
            __syncthreads();
            sp[t] += x;
            __syncthreads();
        }
        int ex = sp[t] - pv;                // exclusive padded offset (multiple of 8)
        int node = b * 256 + t;
        if (node < N) {
            rstart[node] = b * CAP + ex;
            rend[node]   = b * CAP + ex + v;
            dinv[node] = rsqrtf((float)v + 1.0f);   // +1 = self-loop
        }
        // sentinel-fill this node's pad slots (disjoint from all real scatter targets)
        for (int p = ex + v; p < ex + pv && p < CAP; ++p)
            srcs[(size_t)b * CAP + p] = (ushort)N;
        sp[t] = ex;                          // becomes local cursor
        __syncthreads();
        for (int j = t; j < count; j += 256) {
            uint e = eb[j];
            int pos = atomicAdd(&sp[e >> 24], 1);
            if (pos < CAP) srcs[(size_t)b * CAP + pos] = (ushort)(e & 0xFFFFFFu);
        }
    } else {
        // ---------- layer-1 GEMM, fp32 A, 3-product split, UNSCALED output ----------
        const int lane = t & 63;
        const int w = t >> 6;
        const int l15 = lane & 15, quad = lane >> 4;
        const int rowbase = ((int)blockIdx.x - NB) * 128 + w * 32;
        const int M = N;

        f32x4 acc[2][8];
#pragma unroll
        for (int rt = 0; rt < 2; ++rt)
#pragma unroll
            for (int ct = 0; ct < 8; ++ct) acc[rt][ct] = (f32x4){0.f, 0.f, 0.f, 0.f};

        for (int q = 0; q < 4; ++q) {
            frag_u ah[2], al[2];
#pragma unroll
            for (int rt = 0; rt < 2; ++rt) {
                int m = rowbase + rt * 16 + l15;
                if (m >= M) m = M - 1;                  // clamp; stores guarded below
                const float* ap = A + (size_t)m * DF + q * 32 + quad * 8;
                float4 v0 = *(const float4*)ap;
                float4 v1 = *(const float4*)(ap + 4);
                float f[8] = {v0.x, v0.y, v0.z, v0.w, v1.x, v1.y, v1.z, v1.w};
                uint hi[4], lo[4];
#pragma unroll
                for (int p = 0; p < 4; ++p) {
                    uint u0 = f2u(f[2 * p]), u1 = f2u(f[2 * p + 1]);
                    hi[p] = (u1 & 0xFFFF0000u) | (u0 >> 16);
                    float l0 = f[2 * p]     - __uint_as_float(u0 & 0xFFFF0000u);
                    float l1 = f[2 * p + 1] - __uint_as_float(u1 & 0xFFFF0000u);
                    lo[p] = (f2u(l1) & 0xFFFF0000u) | (f2u(l0) >> 16);
                }
                ah[rt].u4 = make_uint4(hi[0], hi[1], hi[2], hi[3]);
                al[rt].u4 = make_uint4(lo[0], lo[1], lo[2], lo[3]);
            }
#pragma unroll
            for (int ct = 0; ct < 8; ++ct) {
                frag_u bh, bl;
                bh.u4 = Bhi[(q * 8 + ct) * 64 + lane];
                bl.u4 = Blo[(q * 8 + ct) * 64 + lane];
#pragma unroll
                for (int rt = 0; rt < 2; ++rt) {
                    acc[rt][ct] = __builtin_amdgcn_mfma_f32_16x16x32_bf16(al[rt].s8, bh.s8, acc[rt][ct], 0, 0, 0);
                    acc[rt][ct] = __builtin_amdgcn_mfma_f32_16x16x32_bf16(ah[rt].s8, bl.s8, acc[rt][ct], 0, 0, 0);
                    acc[rt][ct] = __builtin_amdgcn_mfma_f32_16x16x32_bf16(ah[rt].s8, bh.s8, acc[rt][ct], 0, 0, 0);
                }
            }
        }
        // epilogue: col = ct*16+l15 -> q = ct>>1, d = (ct&1)*16+l15; row = rt*16+quad*4+reg
        // quarter tables have stride M+1 (row M = zeroed sentinel row)
#pragma unroll
        for (int rt = 0; rt < 2; ++rt)
#pragma unroll
            for (int reg = 0; reg < 4; ++reg) {
                int row = rowbase + rt * 16 + quad * 4 + reg;
                if (row < M) {
#pragma unroll
                    for (int ct = 0; ct < 8; ++ct)
                        Hq[((size_t)(ct >> 1) * (M + 1) + row) * 32 + (ct & 1) * 16 + l15] =
                            rne_bf16(acc[rt][ct][reg]);
                }
            }
    }
}

// ============ MFMA GEMM (bf16 A quarter-major): Hq = bf16((A@W)*dinv) ============
// input A (Z1) has stride M; output Hq has stride M+1 (sentinel row stays zero).
__global__ __launch_bounds__(256) void gemm_bf16A(const ushort* __restrict__ A,
                                                  const uint4* __restrict__ Bhi,
                                                  const uint4* __restrict__ Blo,
                                                  const float* __restrict__ dinv,
                                                  ushort* __restrict__ Hq, int M) {
    const int lane = threadIdx.x & 63;
    const int w = threadIdx.x >> 6;
    const int l15 = lane & 15, quad = lane >> 4;
    const int rowbase = blockIdx.x * 128 + w * 32;

    f32x4 acc[2][8];
#pragma unroll
    for (int rt = 0; rt < 2; ++rt)
#pragma unroll
        for (int ct = 0; ct < 8; ++ct) acc[rt][ct] = (f32x4){0.f, 0.f, 0.f, 0.f};

    for (int q = 0; q < 4; ++q) {
        frag_u a[2];
#pragma unroll
        for (int rt = 0; rt < 2; ++rt) {
            int m = rowbase + rt * 16 + l15;
            if (m >= M) m = M - 1;
            const ushort* ap = A + ((size_t)q * M + m) * 32 + quad * 8;
            a[rt].u4 = *(const uint4*)ap;
        }
#pragma unroll
        for (int ct = 0; ct < 8; ++ct) {
            frag_u bh, bl;
            bh.u4 = Bhi[(q * 8 + ct) * 64 + lane];
            bl.u4 = Blo[(q * 8 + ct) * 64 + lane];
#pragma unroll
            for (int rt = 0; rt < 2; ++rt) {
                acc[rt][ct] = __builtin_amdgcn_mfma_f32_16x16x32_bf16(a[rt].s8, bl.s8, acc[rt][ct], 0, 0, 0);
                acc[rt][ct] = __builtin_amdgcn_mfma_f32_16x16x32_bf16(a[rt].s8, bh.s8, acc[rt][ct], 0, 0, 0);
            }
        }
    }
#pragma unroll
    for (int rt = 0; rt < 2; ++rt)
#pragma unroll
        for (int reg = 0; reg < 4; ++reg) {
            int row = rowbase + rt * 16 + quad * 4 + reg;
            if (row < M) {
                float di = dinv[row];
#pragma unroll
                for (int ct = 0; ct < 8; ++ct)
                    Hq[((size_t)(ct >> 1) * (M + 1) + row) * 32 + (ct & 1) * 16 + l15] =
                        rne_bf16(acc[rt][ct][reg] * di);
            }
        }
}

// ---------- gather helpers: issue 8 row loads (+ dinv for L1) / accumulate 8 rows ----------
template<bool L1>
__device__ __forceinline__ void issue8(uint4 sv, const uint4* __restrict__ Hq4, int l,
                                       const float* __restrict__ dinv,
                                       uint4* v, float* d) {
    int si[8];
    si[0] = sv.x & 0xFFFF; si[1] = sv.x >> 16;
    si[2] = sv.y & 0xFFFF; si[3] = sv.y >> 16;
    si[4] = sv.z & 0xFFFF; si[5] = sv.z >> 16;
    si[6] = sv.w & 0xFFFF; si[7] = sv.w >> 16;
#pragma unroll
    for (int i = 0; i < 8; ++i) v[i] = Hq4[(size_t)si[i] * 4 + l];
    if constexpr (L1) {
#pragma unroll
        for (int i = 0; i < 8; ++i) d[i] = dinv[si[i]];         // sentinel -> 0.0f
    }
}

template<bool L1>
__device__ __forceinline__ void acc8(const uint4* v, const float* d, float* a) {
    if constexpr (L1) {
#pragma unroll
        for (int i = 0; i < 8; ++i) {
            a[0] = fmaf(bflo(v[i].x), d[i], a[0]); a[1] = fmaf(bfhi(v[i].x), d[i], a[1]);
            a[2] = fmaf(bflo(v[i].y), d[i], a[2]); a[3] = fmaf(bfhi(v[i].y), d[i], a[3]);
            a[4] = fmaf(bflo(v[i].z), d[i], a[4]); a[5] = fmaf(bfhi(v[i].z), d[i], a[5]);
            a[6] = fmaf(bflo(v[i].w), d[i], a[6]); a[7] = fmaf(bfhi(v[i].w), d[i], a[7]);
        }
    } else {
#pragma unroll
        for (int i = 0; i < 8; ++i) {                           // sentinel rows are zero
            a[0] += bflo(v[i].x); a[1] += bfhi(v[i].x);
            a[2] += bflo(v[i].y); a[3] += bfhi(v[i].y);
            a[4] += bflo(v[i].z); a[5] += bfhi(v[i].z);
            a[6] += bflo(v[i].w); a[7] += bfhi(v[i].w);
        }
    }
}

// ============ quarter gather v9: 2-stage A/B software pipeline ============
// R5 structure (tail-free 8-wide, pad8 sentinels) + NEW: iteration g+1's 8 row loads are
// ISSUED BEFORE iteration g's FMAs consume their rows (indices prefetched 2 ahead).
// The FMA phase then waits on loads issued a full iteration earlier -> per-iteration cost
// drops from (L2 latency + FMA) toward max(residual latency, FMA). Accumulation order per
// node unchanged -> bit-identical. Cost: +~48 VGPR (vB/dB), fine at measured 38% occ.
template<bool L1>
__global__ __launch_bounds__(256) void quarter_gather(const uint4* __restrict__ H4,
                                                      const float* __restrict__ dinv,
                                                      const int* __restrict__ rstart,
                                                      const int* __restrict__ rend,
                                                      const ushort* __restrict__ srcs,
                                                      const float* __restrict__ bias,
                                                      void* __restrict__ outv, int N) {
    int t = threadIdx.x;
    int bid = blockIdx.x;
    int sub = bid & 7;
    int q = sub >> 1;
    int n = (bid >> 3) * 128 + (sub & 1) * 64 + (t >> 2);   // one dst per 4-lane group
    if (n >= N) return;
    int l = t & 3;                                          // lane's uint4 within 64B row
    const uint4* Hq4 = H4 + (size_t)q * (N + 1) * 4;        // quarter table, stride N+1

    float4 bb0 = ((const float4*)bias)[q * 8 + l * 2];
    float4 bb1 = ((const float4*)bias)[q * 8 + l * 2 + 1];

    float di = dinv[n];
    uint4 self = Hq4[(size_t)n * 4 + l];                    // self-loop row
    float sc = L1 ? di : 1.0f;                              // L1: Hq unscaled -> self*di
    float a[8];
    a[0] = bflo(self.x) * sc; a[1] = bfhi(self.x) * sc;
    a[2] = bflo(self.y) * sc; a[3] = bfhi(self.y) * sc;
    a[4] = bflo(self.z) * sc; a[5] = bfhi(self.z) * sc;
    a[6] = bflo(self.w) * sc; a[7] = bfhi(self.w) * sc;

    int j = rstart[n];
    int rem = (rend[n] - j + 7) >> 3;                       // padded trip count (no tail)
    uint4 vA[8], vB[8];
    float dA[8], dB[8];
    uint4 svA, svB;
    if (rem > 0) {
        svA = *(const uint4*)(srcs + j);
        issue8<L1>(svA, Hq4, l, dinv, vA, dA);              // rows for iter 0 in flight
        if (rem > 1) svB = *(const uint4*)(srcs + j + 8);   // indices for iter 1
    }
    while (rem > 0) {
        if (rem > 1) issue8<L1>(svB, Hq4, l, dinv, vB, dB); // issue iter g+1 rows FIRST
        if (rem > 2) svA = *(const uint4*)(srcs + j + 16);  // indices for iter g+2
        acc8<L1>(vA, dA, a);                                // consume iter g (already landed)
        j += 8; --rem;
        if (rem == 0) break;
        if (rem > 1) issue8<L1>(svA, Hq4, l, dinv, vA, dA);
        if (rem > 2) svB = *(const uint4*)(srcs + j + 16);
        acc8<L1>(vB, dB, a);
        j += 8; --rem;
    }
    float o0 = fmaf(a[0], di, bb0.x), o1 = fmaf(a[1], di, bb0.y);
    float o2 = fmaf(a[2], di, bb0.z), o3 = fmaf(a[3], di, bb0.w);
    float o4 = fmaf(a[4], di, bb1.x), o5 = fmaf(a[5], di, bb1.y);
    float o6 = fmaf(a[6], di, bb1.z), o7 = fmaf(a[7], di, bb1.w);
    if (L1) {
        o0 = fmaxf(o0, 0.f); o1 = fmaxf(o1, 0.f); o2 = fmaxf(o2, 0.f); o3 = fmaxf(o3, 0.f);
        o4 = fmaxf(o4, 0.f); o5 = fmaxf(o5, 0.f); o6 = fmaxf(o6, 0.f); o7 = fmaxf(o7, 0.f);
        uint4 pk;
        pk.x = (uint)rne_bf16(o0) | ((uint)rne_bf16(o1) << 16);
        pk.y = (uint)rne_bf16(o2) | ((uint)rne_bf16(o3) << 16);
        pk.z = (uint)rne_bf16(o4) | ((uint)rne_bf16(o5) << 16);
        pk.w = (uint)rne_bf16(o6) | ((uint)rne_bf16(o7) << 16);
        ((uint4*)outv)[((size_t)q * N + n) * 4 + l] = pk;      // Z1 keeps stride N
    } else {
        float4* op = (float4*)((float*)outv + (size_t)n * DF + q * 32 + l * 8);
        op[0] = make_float4(o0, o1, o2, o3);
        op[1] = make_float4(o4, o5, o6, o7);
    }
}

extern "C" void kernel_launch(void* const* d_in, const int* in_sizes, int n_in,
                              void* d_out, int out_size, void* d_ws, size_t ws_size,
                              hipStream_t stream) {
    const float* x  = (const float*)d_in[0];
    const int*   ei = (const int*)d_in[1];
    const float* W1 = (const float*)d_in[2];
    const float* b1 = (const float*)d_in[3];
    const float* W2 = (const float*)d_in[4];
    const float* b2 = (const float*)d_in[5];

    const int N = in_sizes[0] / DF;     // 50000
    const int E = in_sizes[1] / 2;      // 800000
    const int* src = ei;
    const int* dstp = ei + E;
    const int NB = (N + 255) >> 8;      // 196 coarse buckets
    const int SB = (E + SCHUNK - 1) / SCHUNK;   // 391 scatter blocks

    float* out = (float*)d_out;
    char* ws = (char*)d_ws;
    size_t off = 0;
    auto carve = [&](size_t bytes) { void* p = ws + off; off += (bytes + 255) & ~(size_t)255; return p; };
    ushort* Hq     = (ushort*)carve((size_t)4 * (N + 1) * 32 * sizeof(ushort) * 2); // stride N+1
    ushort* Z1     = (ushort*)carve((size_t)N * DF * sizeof(ushort));     // 12.8 MB, stride N
    float*  dinv   = (float*)carve((size_t)(N + 1) * sizeof(float));      // + sentinel slot
    int*    rstart = (int*)carve((size_t)N * sizeof(int));
    int*    rend   = (int*)carve((size_t)N * sizeof(int));
    uint*   ebuf   = (uint*)carve((size_t)NB * CAP * sizeof(uint));       // 6.4 MB
    ushort* srcs   = (ushort*)carve((size_t)NB * CAP * sizeof(ushort));   // 3.2 MB
    int*    ccur   = (int*)carve(NBKT_MAX * sizeof(int));
    uint4*  Whi    = (uint4*)carve(2 * 2048 * sizeof(uint4));             // 64 KB
    uint4*  Wlo    = (uint4*)carve(2 * 2048 * sizeof(uint4));             // 64 KB

    const int gemm_b = (N + 127) / 128;         // 391
    const int gath_b = ((N + 127) / 128) * 8;   // (128-dst chunk) x (2 halves x 4 quarters)

    // ---- D1: CSR scatter (scan-free, regs-cached edges) + W split ----
    hipMemsetAsync(ccur, 0, NBKT_MAX * sizeof(int), stream);
    scatter_wprep<<<SB + 16, 256, 0, stream>>>(src, dstp, ccur, ebuf, E, NB, SB, W1, W2, Whi, Wlo);

    // ---- D2: bucket sort (sentinel-padded segments) || ALL of layer-1 GEMM (unscaled) ----
    sort_gemm1<<<NB + gemm_b, 256, 0, stream>>>(ebuf, ccur, rstart, rend, dinv, srcs,
                                                x, Whi, Wlo, Hq, NB, N);

    // ---- D3: layer 1 gather: Z1 = bf16(relu(di*(self*di + sum dinv[s]*Hq[s]) + b1)) ----
    quarter_gather<true><<<gath_b, 256, 0, stream>>>((const uint4*)Hq, dinv, rstart, rend,
                                                     srcs, b1, Z1, N);

    // ---- D4: layer 2 GEMM: Hq = bf16((Z1@W2)*dinv) ----
    gemm_bf16A<<<gemm_b, 256, 0, stream>>>(Z1, Whi + 2048, Wlo + 2048, dinv, Hq, N);

    // ---- D5: layer 2 gather: out = gather(Hq)*di + b2 ----
    quarter_gather<false><<<gath_b, 256, 0, stream>>>((const uint4*)Hq, dinv, rstart, rend,
                                                      srcs, b2, out, N);
}

// Round 10
// 188.196 us; speedup vs baseline: 1.0576x; 1.0496x over previous
//
#include <hip/hip_runtime.h>

#define DF 128
#define NBKT_MAX 256   // coarse buckets = ceil(N/256); N=50000 -> 196
#define CAP 8192       // per-bucket edge capacity incl. 8-align padding (avg 4082+<=1792 pad)
#define SCHUNK 2048    // edges per scatter block (R2: 8192 -> 3.6% occupancy, latency-bound)
// packing assumes src < 2^24 and N < 65535 (srcs stored as ushort; sentinel = N). N=50000.
//
// SESSION LEDGER (what moved the needle, what didn't):
//   R3 +: scatter 2048-edge chunks + reg-cached dst/src int4 loads (61 -> ~27us)
//   R5 +: sort||gemm1 fusion, sentinel-padded tail-free 8-wide gathers   -> 189.5us BEST
//   R1 -: degree-ranked perm (broke L2 locality of quarter tables, FETCH 27->42MB)
//   R2 -: per-node deg global atomics in scatter (+16us)
//   R4 -: dinv sidecar via split sort (dinv loads were never the gather bottleneck)
//   R6 -: 16-deep gather (MLP saturates at 8; pad16 = +25% issue work)
//   R7 -: scatter||gemm1 (interferes; only sort||gemm1 overlaps cleanly)
//   R8 -: gather||gemm2 (L2 pollution on the table the gather depends on)
//   R9 -: A/B 2-stage gather pipeline (VGPR/occupancy cost > intra-wave overlap)

typedef unsigned int uint;
typedef unsigned short ushort;
typedef __attribute__((ext_vector_type(8))) short short8;   // 8 bf16 (4 VGPR) MFMA A/B frag
typedef __attribute__((ext_vector_type(4))) float f32x4;    // MFMA C/D frag

union frag_u { uint4 u4; short8 s8; };

__device__ __forceinline__ uint f2u(float f) { return __float_as_uint(f); }
__device__ __forceinline__ ushort rne_bf16(float v) {
    uint u = __float_as_uint(v);
    u = u + 0x7FFFu + ((u >> 16) & 1u);
    return (ushort)(u >> 16);
}
__device__ __forceinline__ float bflo(uint u) { return __uint_as_float(u << 16); }
__device__ __forceinline__ float bfhi(uint u) { return __uint_as_float(u & 0xFFFF0000u); }

// ============ scatter + wprep fused (R3 proven) ============
__global__ __launch_bounds__(256) void scatter_wprep(const int* __restrict__ src,
                                                     const int* __restrict__ dst,
                                                     int* __restrict__ ccur,
                                                     uint* __restrict__ ebuf,
                                                     int E, int NB, int SB,
                                                     const float* __restrict__ W1,
                                                     const float* __restrict__ W2,
                                                     uint4* __restrict__ Whi,
                                                     uint4* __restrict__ Wlo) {
    __shared__ int cnt[NBKT_MAX];
    __shared__ int base[NBKT_MAX];
    int t = threadIdx.x;
    if ((int)blockIdx.x < SB) {
        int e0 = blockIdx.x * SCHUNK;
        int eb0 = e0 + t * 8;                       // this thread's 8 contiguous edges
        int lim = min(E - eb0, 8);                  // <8 only in last block
        int d[8], s[8];
        if (lim == 8) {
            int4 d0 = *(const int4*)(dst + eb0), d1 = *(const int4*)(dst + eb0 + 4);
            int4 s0 = *(const int4*)(src + eb0), s1 = *(const int4*)(src + eb0 + 4);
            d[0] = d0.x; d[1] = d0.y; d[2] = d0.z; d[3] = d0.w;
            d[4] = d1.x; d[5] = d1.y; d[6] = d1.z; d[7] = d1.w;
            s[0] = s0.x; s[1] = s0.y; s[2] = s0.z; s[3] = s0.w;
            s[4] = s1.x; s[5] = s1.y; s[6] = s1.z; s[7] = s1.w;
        } else {
            for (int i = 0; i < 8; ++i) { d[i] = 0; s[i] = 0; }
            for (int i = 0; i < lim; ++i) { d[i] = dst[eb0 + i]; s[i] = src[eb0 + i]; }
        }
        for (int i = t; i < NB; i += 256) cnt[i] = 0;
        __syncthreads();
        for (int i = 0; i < 8; ++i)
            if (i < lim) atomicAdd(&cnt[d[i] >> 8], 1);
        __syncthreads();
        for (int i = t; i < NB; i += 256) base[i] = cnt[i] ? atomicAdd(&ccur[i], cnt[i]) : 0;
        __syncthreads();
        for (int i = 0; i < 8; ++i)
            if (i < lim) {
                int b = d[i] >> 8;
                int pos = atomicAdd(&base[b], 1);
                if (pos < CAP) ebuf[(size_t)b * CAP + pos] = ((uint)(d[i] & 255) << 24) | (uint)s[i];
            }
    } else {
        int tt4 = ((int)blockIdx.x - SB) * 256 + t;   // 0..4095
        int wsel = tt4 >> 11;
        int tt = tt4 & 2047;
        const float* W = wsel ? W2 : W1;
        int lane = tt & 63;
        int n  = ((tt >> 6) & 7) * 16 + (lane & 15);
        int k0 = (tt >> 9) * 32 + (lane >> 4) * 8;
        uint hi[4], lo[4];
#pragma unroll
        for (int p = 0; p < 4; ++p) {
            float f0 = W[(size_t)(k0 + 2 * p) * DF + n];
            float f1 = W[(size_t)(k0 + 2 * p + 1) * DF + n];
            uint u0 = f2u(f0), u1 = f2u(f1);
            hi[p] = (u1 & 0xFFFF0000u) | (u0 >> 16);                 // truncation split
            float l0 = f0 - __uint_as_float(u0 & 0xFFFF0000u);       // exact residual
            float l1 = f1 - __uint_as_float(u1 & 0xFFFF0000u);
            lo[p] = (f2u(l1) & 0xFFFF0000u) | (f2u(l0) >> 16);
        }
        Whi[wsel * 2048 + tt] = make_uint4(hi[0], hi[1], hi[2], hi[3]);
        Wlo[wsel * 2048 + tt] = make_uint4(lo[0], lo[1], lo[2], lo[3]);
    }
}

// ============ fused: bucket sort (8-pad sentinel segments) || layer-1 GEMM (UNSCALED) =====
// The ONLY overlap that pays (R7/R8): sort is LDS/atomic-bound, gemm1 is MFMA-bound.
// gemm1 writes UNSCALED Hq (no dinv dependency); gather1 applies dinv[src] via fmaf.
__global__ __launch_bounds__(256) void sort_gemm1(const uint* __restrict__ ebuf,
                                                  const int* __restrict__ ccur,
                                                  int* __restrict__ rstart,
                                                  int* __restrict__ rend,
                                                  float* __restrict__ dinv,
                                                  ushort* __restrict__ srcs,
                                                  const float* __restrict__ A,
                                                  const uint4* __restrict__ Bhi,
                                                  const uint4* __restrict__ Blo,
                                                  ushort* __restrict__ Hq,
                                                  int NB, int N) {
    __shared__ int cnt[256];
    __shared__ int sp[256];
    int t = threadIdx.x;
    if ((int)blockIdx.x < NB) {
        // ---------- bucket sort with 8-aligned, sentinel-padded per-node segments ----------
        int b = blockIdx.x;
        int count = min(ccur[b], CAP);
        const uint* eb = ebuf + (size_t)b * CAP;
        if (b == 0) {                        // one-time: zero dummy rows + dinv sentinel
            if (t < 16) {                    // 4 quarters x 64B dummy row (stride N+1)
                size_t byteoff = ((size_t)(t >> 2) * (N + 1) + N) * 64 + (size_t)(t & 3) * 16;
                *(uint4*)((char*)Hq + byteoff) = make_uint4(0u, 0u, 0u, 0u);
            } else if (t == 16) {
                dinv[N] = 0.0f;              // sentinel scale = 0
            }
        }
        cnt[t] = 0;
        __syncthreads();
        for (int j = t; j < count; j += 256) atomicAdd(&cnt[eb[j] >> 24], 1);
        __syncthreads();
        int v = cnt[t];
        int pv = (v + 7) & ~7;              // padded to multiple of 8
        sp[t] = pv;
        __syncthreads();
        for (int off = 1; off < 256; off <<= 1) {
            int x = (t >= off) ? sp[t - off] : 0;
            __syncthreads();
            sp[t] += x;
            __syncthreads();
        }
        int ex = sp[t] - pv;                // exclusive padded offset (multiple of 8)
        int node = b * 256 + t;
        if (node < N) {
            rstart[node] = b * CAP + ex;
            rend[node]   = b * CAP + ex + v;
            dinv[node] = rsqrtf((float)v + 1.0f);   // +1 = self-loop
        }
        // sentinel-fill this node's pad slots (disjoint from all real scatter targets)
        for (int p = ex + v; p < ex + pv && p < CAP; ++p)
            srcs[(size_t)b * CAP + p] = (ushort)N;
        sp[t] = ex;                          // becomes local cursor
        __syncthreads();
        for (int j = t; j < count; j += 256) {
            uint e = eb[j];
            int pos = atomicAdd(&sp[e >> 24], 1);
            if (pos < CAP) srcs[(size_t)b * CAP + pos] = (ushort)(e & 0xFFFFFFu);
        }
    } else {
        // ---------- layer-1 GEMM, fp32 A, 3-product split, UNSCALED output ----------
        const int lane = t & 63;
        const int w = t >> 6;
        const int l15 = lane & 15, quad = lane >> 4;
        const int rowbase = ((int)blockIdx.x - NB) * 128 + w * 32;
        const int M = N;

        f32x4 acc[2][8];
#pragma unroll
        for (int rt = 0; rt < 2; ++rt)
#pragma unroll
            for (int ct = 0; ct < 8; ++ct) acc[rt][ct] = (f32x4){0.f, 0.f, 0.f, 0.f};

        for (int q = 0; q < 4; ++q) {
            frag_u ah[2], al[2];
#pragma unroll
            for (int rt = 0; rt < 2; ++rt) {
                int m = rowbase + rt * 16 + l15;
                if (m >= M) m = M - 1;                  // clamp; stores guarded below
                const float* ap = A + (size_t)m * DF + q * 32 + quad * 8;
                float4 v0 = *(const float4*)ap;
                float4 v1 = *(const float4*)(ap + 4);
                float f[8] = {v0.x, v0.y, v0.z, v0.w, v1.x, v1.y, v1.z, v1.w};
                uint hi[4], lo[4];
#pragma unroll
                for (int p = 0; p < 4; ++p) {
                    uint u0 = f2u(f[2 * p]), u1 = f2u(f[2 * p + 1]);
                    hi[p] = (u1 & 0xFFFF0000u) | (u0 >> 16);
                    float l0 = f[2 * p]     - __uint_as_float(u0 & 0xFFFF0000u);
                    float l1 = f[2 * p + 1] - __uint_as_float(u1 & 0xFFFF0000u);
                    lo[p] = (f2u(l1) & 0xFFFF0000u) | (f2u(l0) >> 16);
                }
                ah[rt].u4 = make_uint4(hi[0], hi[1], hi[2], hi[3]);
                al[rt].u4 = make_uint4(lo[0], lo[1], lo[2], lo[3]);
            }
#pragma unroll
            for (int ct = 0; ct < 8; ++ct) {
                frag_u bh, bl;
                bh.u4 = Bhi[(q * 8 + ct) * 64 + lane];
                bl.u4 = Blo[(q * 8 + ct) * 64 + lane];
#pragma unroll
                for (int rt = 0; rt < 2; ++rt) {
                    acc[rt][ct] = __builtin_amdgcn_mfma_f32_16x16x32_bf16(al[rt].s8, bh.s8, acc[rt][ct], 0, 0, 0);
                    acc[rt][ct] = __builtin_amdgcn_mfma_f32_16x16x32_bf16(ah[rt].s8, bl.s8, acc[rt][ct], 0, 0, 0);
                    acc[rt][ct] = __builtin_amdgcn_mfma_f32_16x16x32_bf16(ah[rt].s8, bh.s8, acc[rt][ct], 0, 0, 0);
                }
            }
        }
        // epilogue: col = ct*16+l15 -> q = ct>>1, d = (ct&1)*16+l15; row = rt*16+quad*4+reg
        // quarter tables have stride M+1 (row M = zeroed sentinel row)
#pragma unroll
        for (int rt = 0; rt < 2; ++rt)
#pragma unroll
            for (int reg = 0; reg < 4; ++reg) {
                int row = rowbase + rt * 16 + quad * 4 + reg;
                if (row < M) {
#pragma unroll
                    for (int ct = 0; ct < 8; ++ct)
                        Hq[((size_t)(ct >> 1) * (M + 1) + row) * 32 + (ct & 1) * 16 + l15] =
                            rne_bf16(acc[rt][ct][reg]);
                }
            }
    }
}

// ============ MFMA GEMM (bf16 A quarter-major): Hq = bf16((A@W)*dinv) ============
// input A (Z1) has stride M; output Hq has stride M+1 (sentinel row stays zero).
__global__ __launch_bounds__(256) void gemm_bf16A(const ushort* __restrict__ A,
                                                  const uint4* __restrict__ Bhi,
                                                  const uint4* __restrict__ Blo,
                                                  const float* __restrict__ dinv,
                                                  ushort* __restrict__ Hq, int M) {
    const int lane = threadIdx.x & 63;
    const int w = threadIdx.x >> 6;
    const int l15 = lane & 15, quad = lane >> 4;
    const int rowbase = blockIdx.x * 128 + w * 32;

    f32x4 acc[2][8];
#pragma unroll
    for (int rt = 0; rt < 2; ++rt)
#pragma unroll
        for (int ct = 0; ct < 8; ++ct) acc[rt][ct] = (f32x4){0.f, 0.f, 0.f, 0.f};

    for (int q = 0; q < 4; ++q) {
        frag_u a[2];
#pragma unroll
        for (int rt = 0; rt < 2; ++rt) {
            int m = rowbase + rt * 16 + l15;
            if (m >= M) m = M - 1;
            const ushort* ap = A + ((size_t)q * M + m) * 32 + quad * 8;
            a[rt].u4 = *(const uint4*)ap;
        }
#pragma unroll
        for (int ct = 0; ct < 8; ++ct) {
            frag_u bh, bl;
            bh.u4 = Bhi[(q * 8 + ct) * 64 + lane];
            bl.u4 = Blo[(q * 8 + ct) * 64 + lane];
#pragma unroll
            for (int rt = 0; rt < 2; ++rt) {
                acc[rt][ct] = __builtin_amdgcn_mfma_f32_16x16x32_bf16(a[rt].s8, bl.s8, acc[rt][ct], 0, 0, 0);
                acc[rt][ct] = __builtin_amdgcn_mfma_f32_16x16x32_bf16(a[rt].s8, bh.s8, acc[rt][ct], 0, 0, 0);
            }
        }
    }
#pragma unroll
    for (int rt = 0; rt < 2; ++rt)
#pragma unroll
        for (int reg = 0; reg < 4; ++reg) {
            int row = rowbase + rt * 16 + quad * 4 + reg;
            if (row < M) {
                float di = dinv[row];
#pragma unroll
                for (int ct = 0; ct < 8; ++ct)
                    Hq[((size_t)(ct >> 1) * (M + 1) + row) * 32 + (ct & 1) * 16 + l15] =
                        rne_bf16(acc[rt][ct][reg] * di);
            }
        }
}

// ============ quarter gather v7 (R5 BEST): tail-free 8-wide loop ============
// 4-lane groups, uint4/lane (full 64B row per group), direct node order. sub=bid&7 maps
// each XCD to ONE quarter table (3.2MB, L2-resident) — do not break this (R1 lesson).
// Segments sentinel-padded to x8: every iteration is the full 8-rows-in-flight form.
// 8-deep is the measured MLP sweet spot (R6: 16 worse; R9: A/B pipeline worse).
template<bool L1>
__global__ __launch_bounds__(256) void quarter_gather(const uint4* __restrict__ H4,
                                                      const float* __restrict__ dinv,
                                                      const int* __restrict__ rstart,
                                                      const int* __restrict__ rend,
                                                      const ushort* __restrict__ srcs,
                                                      const float* __restrict__ bias,
                                                      void* __restrict__ outv, int N) {
    int t = threadIdx.x;
    int bid = blockIdx.x;
    int sub = bid & 7;
    int q = sub >> 1;
    int n = (bid >> 3) * 128 + (sub & 1) * 64 + (t >> 2);   // one dst per 4-lane group
    if (n >= N) return;
    int l = t & 3;                                          // lane's uint4 within 64B row
    const uint4* Hq4 = H4 + (size_t)q * (N + 1) * 4;        // quarter table, stride N+1

    float4 bb0 = ((const float4*)bias)[q * 8 + l * 2];
    float4 bb1 = ((const float4*)bias)[q * 8 + l * 2 + 1];

    float di = dinv[n];
    uint4 self = Hq4[(size_t)n * 4 + l];                    // self-loop row
    float sc = L1 ? di : 1.0f;                              // L1: Hq unscaled -> self*di
    float a0 = bflo(self.x) * sc, a1 = bfhi(self.x) * sc, a2 = bflo(self.y) * sc, a3 = bfhi(self.y) * sc;
    float a4 = bflo(self.z) * sc, a5 = bfhi(self.z) * sc, a6 = bflo(self.w) * sc, a7 = bfhi(self.w) * sc;

    int j = rstart[n];
    int niter = (rend[n] - j + 7) >> 3;                     // padded trip count (no tail!)
    uint4 sv;
    if (niter > 0) sv = *(const uint4*)(srcs + j);
    for (int g = 0; g < niter; ++g) {
        uint4 svc = sv;
        if (g + 1 < niter) sv = *(const uint4*)(srcs + j + 8);   // prefetch next group
        int si[8];
        si[0] = svc.x & 0xFFFF; si[1] = svc.x >> 16;
        si[2] = svc.y & 0xFFFF; si[3] = svc.y >> 16;
        si[4] = svc.z & 0xFFFF; si[5] = svc.z >> 16;
        si[6] = svc.w & 0xFFFF; si[7] = svc.w >> 16;
        uint4 v[8];
#pragma unroll
        for (int i = 0; i < 8; ++i) v[i] = Hq4[(size_t)si[i] * 4 + l];
        if constexpr (L1) {
            float dd[8];
#pragma unroll
            for (int i = 0; i < 8; ++i) dd[i] = dinv[si[i]];    // sentinel -> 0.0f
#pragma unroll
            for (int i = 0; i < 8; ++i) {
                a0 = fmaf(bflo(v[i].x), dd[i], a0); a1 = fmaf(bfhi(v[i].x), dd[i], a1);
                a2 = fmaf(bflo(v[i].y), dd[i], a2); a3 = fmaf(bfhi(v[i].y), dd[i], a3);
                a4 = fmaf(bflo(v[i].z), dd[i], a4); a5 = fmaf(bfhi(v[i].z), dd[i], a5);
                a6 = fmaf(bflo(v[i].w), dd[i], a6); a7 = fmaf(bfhi(v[i].w), dd[i], a7);
            }
        } else {
#pragma unroll
            for (int i = 0; i < 8; ++i) {                       // sentinel rows are zero
                a0 += bflo(v[i].x); a1 += bfhi(v[i].x);
                a2 += bflo(v[i].y); a3 += bfhi(v[i].y);
                a4 += bflo(v[i].z); a5 += bfhi(v[i].z);
                a6 += bflo(v[i].w); a7 += bfhi(v[i].w);
            }
        }
        j += 8;
    }
    float o0 = fmaf(a0, di, bb0.x), o1 = fmaf(a1, di, bb0.y);
    float o2 = fmaf(a2, di, bb0.z), o3 = fmaf(a3, di, bb0.w);
    float o4 = fmaf(a4, di, bb1.x), o5 = fmaf(a5, di, bb1.y);
    float o6 = fmaf(a6, di, bb1.z), o7 = fmaf(a7, di, bb1.w);
    if (L1) {
        o0 = fmaxf(o0, 0.f); o1 = fmaxf(o1, 0.f); o2 = fmaxf(o2, 0.f); o3 = fmaxf(o3, 0.f);
        o4 = fmaxf(o4, 0.f); o5 = fmaxf(o5, 0.f); o6 = fmaxf(o6, 0.f); o7 = fmaxf(o7, 0.f);
        uint4 pk;
        pk.x = (uint)rne_bf16(o0) | ((uint)rne_bf16(o1) << 16);
        pk.y = (uint)rne_bf16(o2) | ((uint)rne_bf16(o3) << 16);
        pk.z = (uint)rne_bf16(o4) | ((uint)rne_bf16(o5) << 16);
        pk.w = (uint)rne_bf16(o6) | ((uint)rne_bf16(o7) << 16);
        ((uint4*)outv)[((size_t)q * N + n) * 4 + l] = pk;      // Z1 keeps stride N
    } else {
        float4* op = (float4*)((float*)outv + (size_t)n * DF + q * 32 + l * 8);
        op[0] = make_float4(o0, o1, o2, o3);
        op[1] = make_float4(o4, o5, o6, o7);
    }
}

extern "C" void kernel_launch(void* const* d_in, const int* in_sizes, int n_in,
                              void* d_out, int out_size, void* d_ws, size_t ws_size,
                              hipStream_t stream) {
    const float* x  = (const float*)d_in[0];
    const int*   ei = (const int*)d_in[1];
    const float* W1 = (const float*)d_in[2];
    const float* b1 = (const float*)d_in[3];
    const float* W2 = (const float*)d_in[4];
    const float* b2 = (const float*)d_in[5];

    const int N = in_sizes[0] / DF;     // 50000
    const int E = in_sizes[1] / 2;      // 800000
    const int* src = ei;
    const int* dstp = ei + E;
    const int NB = (N + 255) >> 8;      // 196 coarse buckets
    const int SB = (E + SCHUNK - 1) / SCHUNK;   // 391 scatter blocks

    float* out = (float*)d_out;
    char* ws = (char*)d_ws;
    size_t off = 0;
    auto carve = [&](size_t bytes) { void* p = ws + off; off += (bytes + 255) & ~(size_t)255; return p; };
    ushort* Hq     = (ushort*)carve((size_t)4 * (N + 1) * 32 * sizeof(ushort) * 2); // stride N+1
    ushort* Z1     = (ushort*)carve((size_t)N * DF * sizeof(ushort));     // 12.8 MB, stride N
    float*  dinv   = (float*)carve((size_t)(N + 1) * sizeof(float));      // + sentinel slot
    int*    rstart = (int*)carve((size_t)N * sizeof(int));
    int*    rend   = (int*)carve((size_t)N * sizeof(int));
    uint*   ebuf   = (uint*)carve((size_t)NB * CAP * sizeof(uint));       // 6.4 MB
    ushort* srcs   = (ushort*)carve((size_t)NB * CAP * sizeof(ushort));   // 3.2 MB
    int*    ccur   = (int*)carve(NBKT_MAX * sizeof(int));
    uint4*  Whi    = (uint4*)carve(2 * 2048 * sizeof(uint4));             // 64 KB
    uint4*  Wlo    = (uint4*)carve(2 * 2048 * sizeof(uint4));             // 64 KB

    const int gemm_b = (N + 127) / 128;         // 391
    const int gath_b = ((N + 127) / 128) * 8;   // (128-dst chunk) x (2 halves x 4 quarters)

    // ---- D1: CSR scatter (scan-free, regs-cached edges) + W split ----
    hipMemsetAsync(ccur, 0, NBKT_MAX * sizeof(int), stream);
    scatter_wprep<<<SB + 16, 256, 0, stream>>>(src, dstp, ccur, ebuf, E, NB, SB, W1, W2, Whi, Wlo);

    // ---- D2: bucket sort (sentinel-padded segments) || ALL of layer-1 GEMM (unscaled) ----
    sort_gemm1<<<NB + gemm_b, 256, 0, stream>>>(ebuf, ccur, rstart, rend, dinv, srcs,
                                                x, Whi, Wlo, Hq, NB, N);

    // ---- D3: layer 1 gather: Z1 = bf16(relu(di*(self*di + sum dinv[s]*Hq[s]) + b1)) ----
    quarter_gather<true><<<gath_b, 256, 0, stream>>>((const uint4*)Hq, dinv, rstart, rend,
                                                     srcs, b1, Z1, N);

    // ---- D4: layer 2 GEMM: Hq = bf16((Z1@W2)*dinv) ----
    gemm_bf16A<<<gemm_b, 256, 0, stream>>>(Z1, Whi + 2048, Wlo + 2048, dinv, Hq, N);

    // ---- D5: layer 2 gather: out = gather(Hq)*di + b2 ----
    quarter_gather<false><<<gath_b, 256, 0, stream>>>((const uint4*)Hq, dinv, rstart, rend,
                                                      srcs, b2, out, N);
}